// Round 7
// baseline (1293.156 us; speedup 1.0000x reference)
//
#include <hip/hip_runtime.h>
#include <hip/hip_bf16.h>
#include <math.h>

#define N_USERS 50000
#define N_ITEMS 50000
#define N_NODES 100000
#define DIM 64
#define BATCH 2048
#define SLOTS 4096

// graph-2 bucket split: 128 rows per bucket
#define BROWS 128
#define NB 782          // ceil(100000/128)
#define EPB 8192        // edges per scatter block

using frag_ab = __attribute__((ext_vector_type(8))) short;  // 8 bf16
using frag_cd = __attribute__((ext_vector_type(4))) float;  // 4 fp32

// ---------------- helpers ----------------

__device__ __forceinline__ float wave_reduce_sum(float v) {
#pragma unroll
  for (int off = 32; off > 0; off >>= 1)
    v += __shfl_xor(v, off, 64);
  return v;
}

__device__ __forceinline__ int wave_incl_scan_i(int v, int lane) {
#pragma unroll
  for (int off = 1; off < 64; off <<= 1) {
    int t = __shfl_up(v, off, 64);
    if (lane >= off) v += t;
  }
  return v;
}

__device__ __forceinline__ const float* ego_row(const float* ue, const float* ie, int n) {
  return (n < N_USERS) ? (ue + (size_t)n * DIM) : (ie + (size_t)(n - N_USERS) * DIM);
}

__device__ __forceinline__ ushort f2bf(float x) {
  __hip_bfloat16 h = __float2bfloat16(x);
  return *(ushort*)&h;
}

__device__ __forceinline__ float bf2f(ushort u) {
  return __uint_as_float(((unsigned)u) << 16);
}

// ---------------- small setup kernels ----------------

__global__ void build_map_kernel(const int* __restrict__ nu, const int* __restrict__ ni,
                                 int* __restrict__ map) {
  int s = blockIdx.x * blockDim.x + threadIdx.x;
  if (s >= SLOTS) return;
  int n = (s < BATCH) ? nu[s] : (N_USERS + ni[s - BATCH]);
  map[n] = s;
}

// ego -> bf16 (concatenated node-major table xb[100000][64])
__global__ void ego2bf_kernel(const float* __restrict__ ue, const float* __restrict__ ie,
                              ushort* __restrict__ xb) {
  int t = blockIdx.x * blockDim.x + threadIdx.x;  // index of float4 group
  const int TOT = N_NODES * DIM / 4;
  if (t >= TOT) return;
  const int UH = N_USERS * DIM / 4;
  float4 f = (t < UH) ? ((const float4*)ue)[t] : ((const float4*)ie)[t - UH];
  ushort4 o;
  o.x = f2bf(f.x); o.y = f2bf(f.y); o.z = f2bf(f.z); o.w = f2bf(f.w);
  ((ushort4*)xb)[t] = o;
}

// ---------------- graph 2: bucket multi-split + LDS accumulation ----------------

// Pass A: LDS-aggregated histogram of bucket = row>>7.
__global__ __launch_bounds__(256) void bucket_hist_kernel(const int* __restrict__ rows,
                                                          int* __restrict__ bcnt, int nE) {
  __shared__ int cnt[NB];
  int tid = threadIdx.x;
  for (int i = tid; i < NB; i += 256) cnt[i] = 0;
  __syncthreads();
  int e0 = blockIdx.x * EPB;
  for (int i = 0; i < EPB; i += 256) {
    int e = e0 + i + tid;
    if (e < nE) atomicAdd(&cnt[rows[e] >> 7], 1);
  }
  __syncthreads();
  for (int b = tid; b < NB; b += 256)
    if (cnt[b]) atomicAdd(&bcnt[b], cnt[b]);
}

// Pass B: exclusive scan of 782 bucket counts (one 1024-thread block).
__global__ void bucket_scan_kernel(const int* __restrict__ bcnt, int* __restrict__ bcursor) {
  __shared__ int wsum[16];
  int tid = threadIdx.x, lane = tid & 63, wv = tid >> 6;
  int v = (tid < NB) ? bcnt[tid] : 0;
  int incl = wave_incl_scan_i(v, lane);
  if (lane == 63) wsum[wv] = incl;
  __syncthreads();
  if (wv == 0) {
    int s = (lane < 16) ? wsum[lane] : 0;
    int si = wave_incl_scan_i(s, lane);
    if (lane < 16) wsum[lane] = si - s;  // exclusive wave offsets
  }
  __syncthreads();
  int ex = incl - v + wsum[wv];
  if (tid < NB) bcursor[tid] = ex;
  if (tid == NB - 1) bcursor[NB] = ex + v;
}

// Pass C: two-sweep block-level split. After this, bcursor[b] = inclusive
// prefix (end of bucket b) -> serves as rowptr for pass D.
__global__ __launch_bounds__(256) void bucket_scatter_kernel(
    const int* __restrict__ rows, const int* __restrict__ cols,
    const float* __restrict__ vals, int* __restrict__ bcursor,
    int2* __restrict__ brec, int nE) {
  __shared__ int cnt[NB];
  __shared__ int base[NB];
  int tid = threadIdx.x;
  for (int i = tid; i < NB; i += 256) cnt[i] = 0;
  __syncthreads();
  int e0 = blockIdx.x * EPB;
  for (int i = 0; i < EPB; i += 256) {
    int e = e0 + i + tid;
    if (e < nE) atomicAdd(&cnt[rows[e] >> 7], 1);
  }
  __syncthreads();
  for (int b = tid; b < NB; b += 256) {
    int c = cnt[b];
    base[b] = c ? atomicAdd(&bcursor[b], c) : 0;
    cnt[b] = 0;  // reuse as within-block rank counter
  }
  __syncthreads();
  for (int i = 0; i < EPB; i += 256) {
    int e = e0 + i + tid;
    if (e < nE) {
      int r = rows[e];
      int b = r >> 7;
      int rank = atomicAdd(&cnt[b], 1);
      brec[base[b] + rank] =
          make_int2(((r & (BROWS - 1)) << 17) | cols[e], __float_as_int(vals[e]));
    }
  }
}

// Pass D: one block per bucket. 32KB LDS fp32 accumulator; records loaded
// coalesced (64/wave) and shfl-broadcast; per record one contiguous 128B xb
// gather + ds_add_f32. Fused ego-add + l2norm -> zallb.
__global__ __launch_bounds__(256) void bucket_accum_norm_kernel(
    const int* __restrict__ bcursor, const int2* __restrict__ brec,
    const ushort* __restrict__ xb, const float* __restrict__ ue,
    const float* __restrict__ ie, ushort* __restrict__ zallb) {
  __shared__ float lacc[BROWS * DIM];  // 32 KB
  int b = blockIdx.x;
  int tid = threadIdx.x, lane = tid & 63, wave = tid >> 6;
  for (int i = tid; i < BROWS * DIM; i += 256) lacc[i] = 0.f;
  __syncthreads();
  int k0 = (b == 0) ? 0 : bcursor[b - 1];
  int k1 = bcursor[b];
  for (int base = k0; base < k1; base += 256) {
    int idx = base + wave * 64 + lane;
    int2 rec = (idx < k1) ? brec[idx] : make_int2(0, 0);
    int cnt = min(64, k1 - (base + wave * 64));
    int i = 0;
    for (; i + 4 <= cnt; i += 4) {
      float xv[4], vv[4];
      int rl[4];
#pragma unroll
      for (int u = 0; u < 4; u++) {
        int rx = __shfl(rec.x, i + u, 64);
        vv[u] = __int_as_float(__shfl(rec.y, i + u, 64));
        rl[u] = rx >> 17;
        xv[u] = bf2f(xb[(size_t)(rx & 0x1FFFF) * DIM + lane]);
      }
#pragma unroll
      for (int u = 0; u < 4; u++)
        atomicAdd(&lacc[rl[u] * DIM + lane], vv[u] * xv[u]);
    }
    for (; i < cnt; i++) {
      int rx = __shfl(rec.x, i, 64);
      float v = __int_as_float(__shfl(rec.y, i, 64));
      float x = bf2f(xb[(size_t)(rx & 0x1FFFF) * DIM + lane]);
      atomicAdd(&lacc[(rx >> 17) * DIM + lane], v * x);
    }
  }
  __syncthreads();
  int r0g = b * BROWS;
  int nrows = min(BROWS, N_NODES - r0g);
  for (int r = wave; r < nrows; r += 4) {
    int n = r0g + r;
    const float* eg = ego_row(ue, ie, n);
    float w = 0.5f * (eg[lane] + lacc[r * DIM + lane]);
    float ss = wave_reduce_sum(w * w);
    float z = w / fmaxf(sqrtf(ss), 1e-12f);
    zallb[(size_t)n * DIM + lane] = f2bf(z);
  }
}

// ---------------- graph 1: fused filter + accumulate ----------------
__global__ __launch_bounds__(256) void graph1_fused_kernel(
    const int* __restrict__ rows, const int* __restrict__ cols,
    const float* __restrict__ vals, const int* __restrict__ map,
    const ushort* __restrict__ xb, float* __restrict__ z1acc, int nE) {
  __shared__ int lcount;
  __shared__ int hcol[256];
  __shared__ float hval[256];
  __shared__ int hslot[256];
  int tid = threadIdx.x;
  if (tid == 0) lcount = 0;
  __syncthreads();
  int e = blockIdx.x * 256 + tid;
  if (e < nE) {
    int r = rows[e];
    int s = map[r];
    if (s >= 0) {
      int pos = atomicAdd(&lcount, 1);  // LDS atomic - block-local
      hcol[pos] = cols[e];
      hval[pos] = vals[e];
      hslot[pos] = s;
    }
  }
  __syncthreads();
  int n = lcount;
  int wave = tid >> 6, lane = tid & 63;
  for (int k = wave; k < n; k += 4) {
    int c = hcol[k];
    float v = hval[k];
    int s = hslot[k];
    float x = bf2f(xb[(size_t)c * DIM + lane]);
    unsafeAtomicAdd(&z1acc[(size_t)s * DIM + lane], v * x);
  }
}

// z1 normalize (fp32) -> bf16; pos term out -= dot(z1, z2) with z2 from zallb.
__global__ void gather1_kernel(const float* __restrict__ ue, const float* __restrict__ ie,
                               const int* __restrict__ nu, const int* __restrict__ ni,
                               const int* __restrict__ map, const float* __restrict__ z1acc,
                               const ushort* __restrict__ zallb, ushort* __restrict__ z1b,
                               float* __restrict__ out) {
  int s = blockIdx.x * 4 + (threadIdx.x >> 6);
  if (s >= SLOTS) return;
  int lane = threadIdx.x & 63;
  int n = (s < BATCH) ? nu[s] : (N_USERS + ni[s - BATCH]);
  int fs = map[n];
  const float* e = ego_row(ue, ie, n);
  float v = 0.5f * (e[lane] + z1acc[(size_t)fs * DIM + lane]);
  float ss = wave_reduce_sum(v * v);
  float z = v / fmaxf(sqrtf(ss), 1e-12f);
  z1b[(size_t)s * DIM + lane] = f2bf(z);
  float dp = wave_reduce_sum(z * bf2f(zallb[(size_t)n * DIM + lane]));
  if (lane == 0) atomicAdd(out, -dp);
}

// ---------------- ttl (bf16 MFMA) ----------------
#define TTL_STRIPS 125
#define TTL_CHUNKS 25
__global__ __launch_bounds__(256) void ttl_mfma_kernel(const ushort* __restrict__ z1b,
                                                       const ushort* __restrict__ zallb,
                                                       float* __restrict__ ttl) {
  int rb = blockIdx.x / TTL_STRIPS;
  int strip = blockIdx.x % TTL_STRIPS;
  int wave = threadIdx.x >> 6;
  int lane = threadIdx.x & 63;
  int r0 = rb * 128 + wave * 32;
  int side = r0 >> 11;  // rows 0..2047 users, 2048..4095 items
  const ushort* zs = zallb + (size_t)side * N_USERS * DIM;

  int m = lane & 15, q = lane >> 4;
  const ushort* ar0 = z1b + (size_t)(r0 + m) * DIM + q * 8;
  frag_ab a00 = *(const frag_ab*)ar0;
  frag_ab a01 = *(const frag_ab*)(ar0 + 32);
  const ushort* ar1 = ar0 + 16 * DIM;
  frag_ab a10 = *(const frag_ab*)ar1;
  frag_ab a11 = *(const frag_ab*)(ar1 + 32);

  int j0 = strip * (TTL_CHUNKS * 16);
  const ushort* bp = zs + (size_t)(j0 + m) * DIM + q * 8;

  // depth-2 register pipeline on B
  frag_ab b0c = *(const frag_ab*)bp;
  frag_ab b1c = *(const frag_ab*)(bp + 32);
  const ushort* bp1 = bp + 16 * DIM;
  frag_ab b0n = *(const frag_ab*)bp1;
  frag_ab b1n = *(const frag_ab*)(bp1 + 32);

  float racc[8] = {0.f, 0.f, 0.f, 0.f, 0.f, 0.f, 0.f, 0.f};

  for (int c = 0; c < TTL_CHUNKS; c++) {
    frag_ab b0f = b0c, b1f = b1c;
    if (c + 2 < TTL_CHUNKS) {
      const ushort* bp2 = bp + 2 * 16 * DIM;
      b0f = *(const frag_ab*)bp2;
      b1f = *(const frag_ab*)(bp2 + 32);
    }
    frag_cd acc0 = {}, acc1 = {};
    acc0 = __builtin_amdgcn_mfma_f32_16x16x32_bf16(a00, b0c, acc0, 0, 0, 0);
    acc0 = __builtin_amdgcn_mfma_f32_16x16x32_bf16(a01, b1c, acc0, 0, 0, 0);
    acc1 = __builtin_amdgcn_mfma_f32_16x16x32_bf16(a10, b0c, acc1, 0, 0, 0);
    acc1 = __builtin_amdgcn_mfma_f32_16x16x32_bf16(a11, b1c, acc1, 0, 0, 0);
#pragma unroll
    for (int r = 0; r < 4; r++) {
      racc[r] += __expf(2.f * acc0[r]);
      racc[4 + r] += __expf(2.f * acc1[r]);
    }
    b0c = b0n; b1c = b1n;
    b0n = b0f; b1n = b1f;
    bp += 16 * DIM;
  }

  // C layout: col(=zall j) = lane&15, row(=z1 row) = q*4+reg. Reduce over j lanes.
#pragma unroll
  for (int h = 0; h < 2; h++) {
#pragma unroll
    for (int r = 0; r < 4; r++) {
      float v = racc[h * 4 + r];
      v += __shfl_xor(v, 1, 64);
      v += __shfl_xor(v, 2, 64);
      v += __shfl_xor(v, 4, 64);
      v += __shfl_xor(v, 8, 64);
      if (m == 0) atomicAdd(&ttl[r0 + h * 16 + q * 4 + r], v);
    }
  }
}

// out += 0.5 * sum_i log(ttl[i])
__global__ void final_kernel(const float* __restrict__ ttl, float* __restrict__ out) {
  int t = blockIdx.x * blockDim.x + threadIdx.x;
  float v = (t < SLOTS) ? 0.5f * logf(ttl[t]) : 0.f;
  v = wave_reduce_sum(v);
  if ((threadIdx.x & 63) == 0) atomicAdd(out, v);
}

// ---------------- launch ----------------

extern "C" void kernel_launch(void* const* d_in, const int* in_sizes, int n_in,
                              void* d_out, int out_size, void* d_ws, size_t ws_size,
                              hipStream_t stream) {
  const float* ue = (const float*)d_in[0];
  const float* ie = (const float*)d_in[1];
  const int* rows1 = (const int*)d_in[2];
  const int* cols1 = (const int*)d_in[3];
  const float* vals1 = (const float*)d_in[4];
  const int* rows2 = (const int*)d_in[5];
  const int* cols2 = (const int*)d_in[6];
  const float* vals2 = (const float*)d_in[7];
  const int* nu = (const int*)d_in[8];
  const int* ni = (const int*)d_in[9];
  int nE1 = in_sizes[2], nE2 = in_sizes[5];

  // workspace carve-out (256B aligned), total ~43.6 MB
  char* ws = (char*)d_ws;
  size_t o = 0;
  auto carve = [&](size_t bytes) {
    char* p = ws + o;
    o += (bytes + 255) & ~(size_t)255;
    return p;
  };
  int* map = (int*)carve(N_NODES * 4);
  float* z1acc = (float*)carve((size_t)SLOTS * DIM * 4);
  float* ttl = (float*)carve(SLOTS * 4);
  ushort* zallb = (ushort*)carve((size_t)N_NODES * DIM * 2);
  ushort* z1b = (ushort*)carve((size_t)SLOTS * DIM * 2);
  ushort* xb = (ushort*)carve((size_t)N_NODES * DIM * 2);
  int* bcnt = (int*)carve(NB * 4);
  int* bcursor = (int*)carve((NB + 1) * 4);
  int2* brec = (int2*)carve((size_t)nE2 * 8);
  float* out = (float*)d_out;

  hipMemsetAsync(map, 0xFF, N_NODES * 4, stream);  // -1
  hipMemsetAsync(z1acc, 0, (size_t)SLOTS * DIM * 4, stream);
  hipMemsetAsync(ttl, 0, SLOTS * 4, stream);
  hipMemsetAsync(bcnt, 0, NB * 4, stream);
  hipMemsetAsync(out, 0, sizeof(float), stream);

  int nsb = (nE2 + EPB - 1) / EPB;  // 245 split blocks

  build_map_kernel<<<16, 256, 0, stream>>>(nu, ni, map);
  ego2bf_kernel<<<(N_NODES * DIM / 4 + 255) / 256, 256, 0, stream>>>(ue, ie, xb);
  bucket_hist_kernel<<<nsb, 256, 0, stream>>>(rows2, bcnt, nE2);
  bucket_scan_kernel<<<1, 1024, 0, stream>>>(bcnt, bcursor);
  bucket_scatter_kernel<<<nsb, 256, 0, stream>>>(rows2, cols2, vals2, bcursor, brec, nE2);
  bucket_accum_norm_kernel<<<NB, 256, 0, stream>>>(bcursor, brec, xb, ue, ie, zallb);
  graph1_fused_kernel<<<(nE1 + 255) / 256, 256, 0, stream>>>(rows1, cols1, vals1, map, xb, z1acc, nE1);
  gather1_kernel<<<SLOTS / 4, 256, 0, stream>>>(ue, ie, nu, ni, map, z1acc, zallb, z1b, out);
  ttl_mfma_kernel<<<32 * TTL_STRIPS, 256, 0, stream>>>(z1b, zallb, ttl);
  final_kernel<<<16, 256, 0, stream>>>(ttl, out);
}

// Round 8
// 712.059 us; speedup vs baseline: 1.8161x; 1.8161x over previous
//
#include <hip/hip_runtime.h>
#include <hip/hip_bf16.h>
#include <math.h>

#define N_USERS 50000
#define N_ITEMS 50000
#define N_NODES 100000
#define DIM 64
#define BATCH 2048
#define SLOTS 4096

using frag_ab = __attribute__((ext_vector_type(8))) short;  // 8 bf16
using frag_cd = __attribute__((ext_vector_type(4))) float;  // 4 fp32

// ---------------- helpers ----------------

__device__ __forceinline__ float wave_reduce_sum(float v) {
#pragma unroll
  for (int off = 32; off > 0; off >>= 1)
    v += __shfl_xor(v, off, 64);
  return v;
}

__device__ __forceinline__ const float* ego_row(const float* ue, const float* ie, int n) {
  return (n < N_USERS) ? (ue + (size_t)n * DIM) : (ie + (size_t)(n - N_USERS) * DIM);
}

__device__ __forceinline__ ushort f2bf(float x) {
  __hip_bfloat16 h = __float2bfloat16(x);
  return *(ushort*)&h;
}

__device__ __forceinline__ float bf2f(ushort u) {
  return __uint_as_float(((unsigned)u) << 16);
}

// ---------------- small setup kernels ----------------

__global__ void build_map_kernel(const int* __restrict__ nu, const int* __restrict__ ni,
                                 int* __restrict__ map) {
  int s = blockIdx.x * blockDim.x + threadIdx.x;
  if (s >= SLOTS) return;
  int n = (s < BATCH) ? nu[s] : (N_USERS + ni[s - BATCH]);
  map[n] = s;
}

// ego -> bf16 (concatenated node-major table xb[100000][64])
__global__ void ego2bf_kernel(const float* __restrict__ ue, const float* __restrict__ ie,
                              ushort* __restrict__ xb) {
  int t = blockIdx.x * blockDim.x + threadIdx.x;  // index of float4 group
  const int TOT = N_NODES * DIM / 4;
  if (t >= TOT) return;
  const int UH = N_USERS * DIM / 4;
  float4 f = (t < UH) ? ((const float4*)ue)[t] : ((const float4*)ie)[t - UH];
  ushort4 o;
  o.x = f2bf(f.x); o.y = f2bf(f.y); o.z = f2bf(f.z); o.w = f2bf(f.w);
  ((ushort4*)xb)[t] = o;
}

// ---------------- graph 2: per-row linked list with PACKED 8B records ---------
// rec[e] = {next, col} written coalesced by e. Degree histogram fused in.
// Walk then touches ONE random line per step instead of three (R6: 406MB fetch).
__global__ void link2_kernel(const int* __restrict__ rows, const int* __restrict__ cols,
                             int* __restrict__ head, int* __restrict__ deg,
                             int2* __restrict__ rec, int nE) {
  int e = blockIdx.x * blockDim.x + threadIdx.x;
  if (e >= nE) return;
  int r = rows[e];
  atomicAdd(&deg[r], 1);
  int nx = atomicExch(&head[r], e);
  rec[e] = make_int2(nx, cols[e]);
}

// Wave-per-node chain walk. Per step: one wave-uniform 8B rec load (the only
// random line), one 4B deg[c] (L2-resident 400KB), one contiguous 128B xb row.
// val = rsqrt(deg[n])*rsqrt(deg[c]) reconstructs the symmetric normalization.
// Fused 0.5*(ego+.) + l2norm -> zallb.
__global__ void gather_chain_norm_kernel(const int* __restrict__ head,
                                         const int2* __restrict__ rec,
                                         const int* __restrict__ deg,
                                         const ushort* __restrict__ xb,
                                         const float* __restrict__ ue,
                                         const float* __restrict__ ie,
                                         ushort* __restrict__ zallb) {
  int n = blockIdx.x * 4 + (threadIdx.x >> 6);
  if (n >= N_NODES) return;
  int lane = threadIdx.x & 63;
  float dinvn = rsqrtf((float)max(deg[n], 1));
  float acc = 0.f;
  int e = head[n];
  while (e >= 0) {
    int2 rc = rec[e];  // wave-broadcast: {next, col}
    int c = rc.y;
    float dc = rsqrtf((float)deg[c]);  // deg[c]>=1 (symmetric graph)
    acc = fmaf(dinvn * dc, bf2f(xb[(size_t)c * DIM + lane]), acc);
    e = rc.x;
  }
  const float* eg = ego_row(ue, ie, n);
  float w = 0.5f * (eg[lane] + acc);
  float ss = wave_reduce_sum(w * w);
  float z = w / fmaxf(sqrtf(ss), 1e-12f);
  zallb[(size_t)n * DIM + lane] = f2bf(z);
}

// ---------------- graph 1: fused filter + accumulate ----------------
// Per-block LDS compaction, then the block's 4 waves gather xb rows and
// atomic-accumulate into the L2-resident 1MB z1acc.
__global__ __launch_bounds__(256) void graph1_fused_kernel(
    const int* __restrict__ rows, const int* __restrict__ cols,
    const float* __restrict__ vals, const int* __restrict__ map,
    const ushort* __restrict__ xb, float* __restrict__ z1acc, int nE) {
  __shared__ int lcount;
  __shared__ int hcol[256];
  __shared__ float hval[256];
  __shared__ int hslot[256];
  int tid = threadIdx.x;
  if (tid == 0) lcount = 0;
  __syncthreads();
  int e = blockIdx.x * 256 + tid;
  if (e < nE) {
    int r = rows[e];
    int s = map[r];
    if (s >= 0) {
      int pos = atomicAdd(&lcount, 1);  // LDS atomic - block-local
      hcol[pos] = cols[e];
      hval[pos] = vals[e];
      hslot[pos] = s;
    }
  }
  __syncthreads();
  int n = lcount;
  int wave = tid >> 6, lane = tid & 63;
  for (int k = wave; k < n; k += 4) {
    int c = hcol[k];
    float v = hval[k];
    int s = hslot[k];
    float x = bf2f(xb[(size_t)c * DIM + lane]);
    unsafeAtomicAdd(&z1acc[(size_t)s * DIM + lane], v * x);
  }
}

// z1 normalize (fp32) -> bf16; pos term out -= dot(z1, z2) with z2 from zallb.
__global__ void gather1_kernel(const float* __restrict__ ue, const float* __restrict__ ie,
                               const int* __restrict__ nu, const int* __restrict__ ni,
                               const int* __restrict__ map, const float* __restrict__ z1acc,
                               const ushort* __restrict__ zallb, ushort* __restrict__ z1b,
                               float* __restrict__ out) {
  int s = blockIdx.x * 4 + (threadIdx.x >> 6);
  if (s >= SLOTS) return;
  int lane = threadIdx.x & 63;
  int n = (s < BATCH) ? nu[s] : (N_USERS + ni[s - BATCH]);
  int fs = map[n];
  const float* e = ego_row(ue, ie, n);
  float v = 0.5f * (e[lane] + z1acc[(size_t)fs * DIM + lane]);
  float ss = wave_reduce_sum(v * v);
  float z = v / fmaxf(sqrtf(ss), 1e-12f);
  z1b[(size_t)s * DIM + lane] = f2bf(z);
  float dp = wave_reduce_sum(z * bf2f(zallb[(size_t)n * DIM + lane]));
  if (lane == 0) atomicAdd(out, -dp);
}

// ---------------- ttl (bf16 MFMA) ----------------
// Wave tile: M=32 z1 rows x 16 j per chunk, K=64 -> 4 MFMAs/chunk.
// Block = 4 waves = 128 rows, one strip of 25 chunks (400 j). Grid 32x125.
#define TTL_STRIPS 125
#define TTL_CHUNKS 25
__global__ __launch_bounds__(256) void ttl_mfma_kernel(const ushort* __restrict__ z1b,
                                                       const ushort* __restrict__ zallb,
                                                       float* __restrict__ ttl) {
  int rb = blockIdx.x / TTL_STRIPS;
  int strip = blockIdx.x % TTL_STRIPS;
  int wave = threadIdx.x >> 6;
  int lane = threadIdx.x & 63;
  int r0 = rb * 128 + wave * 32;
  int side = r0 >> 11;  // rows 0..2047 users, 2048..4095 items
  const ushort* zs = zallb + (size_t)side * N_USERS * DIM;

  int m = lane & 15, q = lane >> 4;
  const ushort* ar0 = z1b + (size_t)(r0 + m) * DIM + q * 8;
  frag_ab a00 = *(const frag_ab*)ar0;
  frag_ab a01 = *(const frag_ab*)(ar0 + 32);
  const ushort* ar1 = ar0 + 16 * DIM;
  frag_ab a10 = *(const frag_ab*)ar1;
  frag_ab a11 = *(const frag_ab*)(ar1 + 32);

  int j0 = strip * (TTL_CHUNKS * 16);
  const ushort* bp = zs + (size_t)(j0 + m) * DIM + q * 8;

  // depth-2 register pipeline on B
  frag_ab b0c = *(const frag_ab*)bp;
  frag_ab b1c = *(const frag_ab*)(bp + 32);
  const ushort* bp1 = bp + 16 * DIM;
  frag_ab b0n = *(const frag_ab*)bp1;
  frag_ab b1n = *(const frag_ab*)(bp1 + 32);

  float racc[8] = {0.f, 0.f, 0.f, 0.f, 0.f, 0.f, 0.f, 0.f};

  for (int c = 0; c < TTL_CHUNKS; c++) {
    frag_ab b0f = b0c, b1f = b1c;
    if (c + 2 < TTL_CHUNKS) {
      const ushort* bp2 = bp + 2 * 16 * DIM;
      b0f = *(const frag_ab*)bp2;
      b1f = *(const frag_ab*)(bp2 + 32);
    }
    frag_cd acc0 = {}, acc1 = {};
    acc0 = __builtin_amdgcn_mfma_f32_16x16x32_bf16(a00, b0c, acc0, 0, 0, 0);
    acc0 = __builtin_amdgcn_mfma_f32_16x16x32_bf16(a01, b1c, acc0, 0, 0, 0);
    acc1 = __builtin_amdgcn_mfma_f32_16x16x32_bf16(a10, b0c, acc1, 0, 0, 0);
    acc1 = __builtin_amdgcn_mfma_f32_16x16x32_bf16(a11, b1c, acc1, 0, 0, 0);
#pragma unroll
    for (int r = 0; r < 4; r++) {
      racc[r] += __expf(2.f * acc0[r]);
      racc[4 + r] += __expf(2.f * acc1[r]);
    }
    b0c = b0n; b1c = b1n;
    b0n = b0f; b1n = b1f;
    bp += 16 * DIM;
  }

  // C layout: col(=zall j) = lane&15, row(=z1 row) = q*4+reg. Reduce over j lanes.
#pragma unroll
  for (int h = 0; h < 2; h++) {
#pragma unroll
    for (int r = 0; r < 4; r++) {
      float v = racc[h * 4 + r];
      v += __shfl_xor(v, 1, 64);
      v += __shfl_xor(v, 2, 64);
      v += __shfl_xor(v, 4, 64);
      v += __shfl_xor(v, 8, 64);
      if (m == 0) atomicAdd(&ttl[r0 + h * 16 + q * 4 + r], v);
    }
  }
}

// out += 0.5 * sum_i log(ttl[i])
__global__ void final_kernel(const float* __restrict__ ttl, float* __restrict__ out) {
  int t = blockIdx.x * blockDim.x + threadIdx.x;
  float v = (t < SLOTS) ? 0.5f * logf(ttl[t]) : 0.f;
  v = wave_reduce_sum(v);
  if ((threadIdx.x & 63) == 0) atomicAdd(out, v);
}

// ---------------- launch ----------------

extern "C" void kernel_launch(void* const* d_in, const int* in_sizes, int n_in,
                              void* d_out, int out_size, void* d_ws, size_t ws_size,
                              hipStream_t stream) {
  const float* ue = (const float*)d_in[0];
  const float* ie = (const float*)d_in[1];
  const int* rows1 = (const int*)d_in[2];
  const int* cols1 = (const int*)d_in[3];
  const float* vals1 = (const float*)d_in[4];
  const int* rows2 = (const int*)d_in[5];
  const int* cols2 = (const int*)d_in[6];
  const float* vals2 = (const float*)d_in[7];
  const int* nu = (const int*)d_in[8];
  const int* ni = (const int*)d_in[9];
  int nE1 = in_sizes[2], nE2 = in_sizes[5];
  (void)vals2;

  // workspace carve-out (256B aligned), total ~44.4 MB
  char* ws = (char*)d_ws;
  size_t o = 0;
  auto carve = [&](size_t bytes) {
    char* p = ws + o;
    o += (bytes + 255) & ~(size_t)255;
    return p;
  };
  int* map = (int*)carve(N_NODES * 4);
  float* z1acc = (float*)carve((size_t)SLOTS * DIM * 4);
  float* ttl = (float*)carve(SLOTS * 4);
  ushort* zallb = (ushort*)carve((size_t)N_NODES * DIM * 2);
  ushort* z1b = (ushort*)carve((size_t)SLOTS * DIM * 2);
  ushort* xb = (ushort*)carve((size_t)N_NODES * DIM * 2);
  int* head = (int*)carve(N_NODES * 4);
  int* deg = (int*)carve(N_NODES * 4);
  int2* rec = (int2*)carve((size_t)nE2 * 8);
  float* out = (float*)d_out;

  hipMemsetAsync(map, 0xFF, N_NODES * 4, stream);   // -1
  hipMemsetAsync(head, 0xFF, N_NODES * 4, stream);  // -1
  hipMemsetAsync(deg, 0, N_NODES * 4, stream);
  hipMemsetAsync(z1acc, 0, (size_t)SLOTS * DIM * 4, stream);
  hipMemsetAsync(ttl, 0, SLOTS * 4, stream);
  hipMemsetAsync(out, 0, sizeof(float), stream);

  build_map_kernel<<<16, 256, 0, stream>>>(nu, ni, map);
  ego2bf_kernel<<<(N_NODES * DIM / 4 + 255) / 256, 256, 0, stream>>>(ue, ie, xb);
  link2_kernel<<<(nE2 + 255) / 256, 256, 0, stream>>>(rows2, cols2, head, deg, rec, nE2);
  gather_chain_norm_kernel<<<(N_NODES + 3) / 4, 256, 0, stream>>>(head, rec, deg, xb, ue, ie,
                                                                  zallb);
  graph1_fused_kernel<<<(nE1 + 255) / 256, 256, 0, stream>>>(rows1, cols1, vals1, map, xb, z1acc, nE1);
  gather1_kernel<<<SLOTS / 4, 256, 0, stream>>>(ue, ie, nu, ni, map, z1acc, zallb, z1b, out);
  ttl_mfma_kernel<<<32 * TTL_STRIPS, 256, 0, stream>>>(z1b, zallb, ttl);
  final_kernel<<<16, 256, 0, stream>>>(ttl, out);
}

// Round 11
// 571.548 us; speedup vs baseline: 2.2626x; 1.2458x over previous
//
#include <hip/hip_runtime.h>
#include <hip/hip_bf16.h>
#include <hip/hip_fp16.h>
#include <math.h>

#define N_USERS 50000
#define N_ITEMS 50000
#define N_NODES 100000
#define DIM 64
#define BATCH 2048
#define SLOTS 4096

using frag_ab = __attribute__((ext_vector_type(8))) short;  // 8 bf16
using frag_cd = __attribute__((ext_vector_type(4))) float;  // 4 fp32
typedef unsigned long long u64;

// ---------------- helpers ----------------

__device__ __forceinline__ float wave_reduce_sum(float v) {
#pragma unroll
  for (int off = 32; off > 0; off >>= 1)
    v += __shfl_xor(v, off, 64);
  return v;
}

__device__ __forceinline__ const float* ego_row(const float* ue, const float* ie, int n) {
  return (n < N_USERS) ? (ue + (size_t)n * DIM) : (ie + (size_t)(n - N_USERS) * DIM);
}

__device__ __forceinline__ ushort f2bf(float x) {
  __hip_bfloat16 h = __float2bfloat16(x);
  return *(ushort*)&h;
}

__device__ __forceinline__ float bf2f(ushort u) {
  return __uint_as_float(((unsigned)u) << 16);
}

// ---------------- small setup kernels ----------------

__global__ void build_map_kernel(const int* __restrict__ nu, const int* __restrict__ ni,
                                 int* __restrict__ map) {
  int s = blockIdx.x * blockDim.x + threadIdx.x;
  if (s >= SLOTS) return;
  int n = (s < BATCH) ? nu[s] : (N_USERS + ni[s - BATCH]);
  map[n] = s;
}

// ego -> bf16 (concatenated node-major table xb[100000][64])
__global__ void ego2bf_kernel(const float* __restrict__ ue, const float* __restrict__ ie,
                              ushort* __restrict__ xb) {
  int t = blockIdx.x * blockDim.x + threadIdx.x;  // index of float4 group
  const int TOT = N_NODES * DIM / 4;
  if (t >= TOT) return;
  const int UH = N_USERS * DIM / 4;
  float4 f = (t < UH) ? ((const float4*)ue)[t] : ((const float4*)ie)[t - UH];
  ushort4 o;
  o.x = f2bf(f.x); o.y = f2bf(f.y); o.z = f2bf(f.z); o.w = f2bf(f.w);
  ((ushort4*)xb)[t] = o;
}

// ---------------- graph 2: per-row linked list, 8B records with val fused -----
// rec[e] = val_f16<<48 | col<<24 | (next+1). One atomicExch/edge; rec written
// coalesced by e. Walk touches ONE random line per step, no deg/vals lookups.
__global__ void link2_kernel(const int* __restrict__ rows, const int* __restrict__ cols,
                             const float* __restrict__ vals, int* __restrict__ head,
                             u64* __restrict__ rec, int nE) {
  int e = blockIdx.x * blockDim.x + threadIdx.x;
  if (e >= nE) return;
  int r = rows[e];
  int nx = atomicExch(&head[r], e + 1);  // head encoded +1, 0 = empty
  ushort hb = __half_as_ushort(__float2half(vals[e]));
  rec[e] = ((u64)hb << 48) | ((u64)(cols[e] & 0x1FFFF) << 24) | (u64)(unsigned)nx;
}

// ILP-4 chain walk: each wave walks 4 node chains concurrently, staged so the
// 4 dependent rec-chases overlap (4x memory-level parallelism per wave).
// All chain pointers are lane-uniform -> wave-uniform branches.
// Fused 0.5*(ego+.) + l2norm -> zallb.
__global__ void gather_chain_norm_kernel(const int* __restrict__ head,
                                         const u64* __restrict__ rec,
                                         const ushort* __restrict__ xb,
                                         const float* __restrict__ ue,
                                         const float* __restrict__ ie,
                                         ushort* __restrict__ zallb) {
  int n0 = (blockIdx.x * 4 + (threadIdx.x >> 6)) * 4;  // 4 nodes per wave
  if (n0 >= N_NODES) return;
  int lane = threadIdx.x & 63;
  float acc[4] = {0.f, 0.f, 0.f, 0.f};
  int e[4];
#pragma unroll
  for (int i = 0; i < 4; i++) e[i] = (n0 + i < N_NODES) ? head[n0 + i] : 0;

  while (e[0] | e[1] | e[2] | e[3]) {
    u64 u[4];
#pragma unroll
    for (int i = 0; i < 4; i++)
      if (e[i]) u[i] = rec[e[i] - 1];  // 4 independent random 8B loads
    float x[4];
#pragma unroll
    for (int i = 0; i < 4; i++)
      if (e[i]) {
        int c = (int)((u[i] >> 24) & 0x1FFFF);
        x[i] = bf2f(xb[(size_t)c * DIM + lane]);  // 4 independent 128B rows
      }
#pragma unroll
    for (int i = 0; i < 4; i++)
      if (e[i]) {
        float v = __half2float(__ushort_as_half((ushort)(u[i] >> 48)));
        acc[i] = fmaf(v, x[i], acc[i]);
        e[i] = (int)(u[i] & 0xFFFFFF);
      }
  }

#pragma unroll
  for (int i = 0; i < 4; i++) {
    int n = n0 + i;
    if (n >= N_NODES) break;
    const float* eg = ego_row(ue, ie, n);
    float w = 0.5f * (eg[lane] + acc[i]);
    float ss = wave_reduce_sum(w * w);
    float z = w / fmaxf(sqrtf(ss), 1e-12f);
    zallb[(size_t)n * DIM + lane] = f2bf(z);
  }
}

// ---------------- graph 1: fused filter + accumulate ----------------
// Per-block LDS compaction, then the block's 4 waves gather xb rows and
// atomic-accumulate into the L2-resident 1MB z1acc.
__global__ __launch_bounds__(256) void graph1_fused_kernel(
    const int* __restrict__ rows, const int* __restrict__ cols,
    const float* __restrict__ vals, const int* __restrict__ map,
    const ushort* __restrict__ xb, float* __restrict__ z1acc, int nE) {
  __shared__ int lcount;
  __shared__ int hcol[256];
  __shared__ float hval[256];
  __shared__ int hslot[256];
  int tid = threadIdx.x;
  if (tid == 0) lcount = 0;
  __syncthreads();
  int e = blockIdx.x * 256 + tid;
  if (e < nE) {
    int r = rows[e];
    int s = map[r];
    if (s >= 0) {
      int pos = atomicAdd(&lcount, 1);  // LDS atomic - block-local
      hcol[pos] = cols[e];
      hval[pos] = vals[e];
      hslot[pos] = s;
    }
  }
  __syncthreads();
  int n = lcount;
  int wave = tid >> 6, lane = tid & 63;
  for (int k = wave; k < n; k += 4) {
    int c = hcol[k];
    float v = hval[k];
    int s = hslot[k];
    float x = bf2f(xb[(size_t)c * DIM + lane]);
    unsafeAtomicAdd(&z1acc[(size_t)s * DIM + lane], v * x);
  }
}

// z1 normalize (fp32) -> bf16; pos term out -= dot(z1, z2) with z2 from zallb.
__global__ void gather1_kernel(const float* __restrict__ ue, const float* __restrict__ ie,
                               const int* __restrict__ nu, const int* __restrict__ ni,
                               const int* __restrict__ map, const float* __restrict__ z1acc,
                               const ushort* __restrict__ zallb, ushort* __restrict__ z1b,
                               float* __restrict__ out) {
  int s = blockIdx.x * 4 + (threadIdx.x >> 6);
  if (s >= SLOTS) return;
  int lane = threadIdx.x & 63;
  int n = (s < BATCH) ? nu[s] : (N_USERS + ni[s - BATCH]);
  int fs = map[n];
  const float* e = ego_row(ue, ie, n);
  float v = 0.5f * (e[lane] + z1acc[(size_t)fs * DIM + lane]);
  float ss = wave_reduce_sum(v * v);
  float z = v / fmaxf(sqrtf(ss), 1e-12f);
  z1b[(size_t)s * DIM + lane] = f2bf(z);
  float dp = wave_reduce_sum(z * bf2f(zallb[(size_t)n * DIM + lane]));
  if (lane == 0) atomicAdd(out, -dp);
}

// ---------------- ttl (bf16 MFMA) ----------------
// Wave tile: M=32 z1 rows x 16 j per chunk, K=64 -> 4 MFMAs/chunk.
// Block = 4 waves = 128 rows, one strip of 25 chunks (400 j). Grid 32x125.
#define TTL_STRIPS 125
#define TTL_CHUNKS 25
__global__ __launch_bounds__(256) void ttl_mfma_kernel(const ushort* __restrict__ z1b,
                                                       const ushort* __restrict__ zallb,
                                                       float* __restrict__ ttl) {
  int rb = blockIdx.x / TTL_STRIPS;
  int strip = blockIdx.x % TTL_STRIPS;
  int wave = threadIdx.x >> 6;
  int lane = threadIdx.x & 63;
  int r0 = rb * 128 + wave * 32;
  int side = r0 >> 11;  // rows 0..2047 users, 2048..4095 items
  const ushort* zs = zallb + (size_t)side * N_USERS * DIM;

  int m = lane & 15, q = lane >> 4;
  const ushort* ar0 = z1b + (size_t)(r0 + m) * DIM + q * 8;
  frag_ab a00 = *(const frag_ab*)ar0;
  frag_ab a01 = *(const frag_ab*)(ar0 + 32);
  const ushort* ar1 = ar0 + 16 * DIM;
  frag_ab a10 = *(const frag_ab*)ar1;
  frag_ab a11 = *(const frag_ab*)(ar1 + 32);

  int j0 = strip * (TTL_CHUNKS * 16);
  const ushort* bp = zs + (size_t)(j0 + m) * DIM + q * 8;

  // depth-2 register pipeline on B
  frag_ab b0c = *(const frag_ab*)bp;
  frag_ab b1c = *(const frag_ab*)(bp + 32);
  const ushort* bp1 = bp + 16 * DIM;
  frag_ab b0n = *(const frag_ab*)bp1;
  frag_ab b1n = *(const frag_ab*)(bp1 + 32);

  float racc[8] = {0.f, 0.f, 0.f, 0.f, 0.f, 0.f, 0.f, 0.f};

  for (int c = 0; c < TTL_CHUNKS; c++) {
    frag_ab b0f = b0c, b1f = b1c;
    if (c + 2 < TTL_CHUNKS) {
      const ushort* bp2 = bp + 2 * 16 * DIM;
      b0f = *(const frag_ab*)bp2;
      b1f = *(const frag_ab*)(bp2 + 32);
    }
    frag_cd acc0 = {}, acc1 = {};
    acc0 = __builtin_amdgcn_mfma_f32_16x16x32_bf16(a00, b0c, acc0, 0, 0, 0);
    acc0 = __builtin_amdgcn_mfma_f32_16x16x32_bf16(a01, b1c, acc0, 0, 0, 0);
    acc1 = __builtin_amdgcn_mfma_f32_16x16x32_bf16(a10, b0c, acc1, 0, 0, 0);
    acc1 = __builtin_amdgcn_mfma_f32_16x16x32_bf16(a11, b1c, acc1, 0, 0, 0);
#pragma unroll
    for (int r = 0; r < 4; r++) {
      racc[r] += __expf(2.f * acc0[r]);
      racc[4 + r] += __expf(2.f * acc1[r]);
    }
    b0c = b0n; b1c = b1n;
    b0n = b0f; b1n = b1f;
    bp += 16 * DIM;
  }

  // C layout: col(=zall j) = lane&15, row(=z1 row) = q*4+reg. Reduce over j lanes.
#pragma unroll
  for (int h = 0; h < 2; h++) {
#pragma unroll
    for (int r = 0; r < 4; r++) {
      float v = racc[h * 4 + r];
      v += __shfl_xor(v, 1, 64);
      v += __shfl_xor(v, 2, 64);
      v += __shfl_xor(v, 4, 64);
      v += __shfl_xor(v, 8, 64);
      if (m == 0) atomicAdd(&ttl[r0 + h * 16 + q * 4 + r], v);
    }
  }
}

// out += 0.5 * sum_i log(ttl[i])
__global__ void final_kernel(const float* __restrict__ ttl, float* __restrict__ out) {
  int t = blockIdx.x * blockDim.x + threadIdx.x;
  float v = (t < SLOTS) ? 0.5f * logf(ttl[t]) : 0.f;
  v = wave_reduce_sum(v);
  if ((threadIdx.x & 63) == 0) atomicAdd(out, v);
}

// ---------------- launch ----------------

extern "C" void kernel_launch(void* const* d_in, const int* in_sizes, int n_in,
                              void* d_out, int out_size, void* d_ws, size_t ws_size,
                              hipStream_t stream) {
  const float* ue = (const float*)d_in[0];
  const float* ie = (const float*)d_in[1];
  const int* rows1 = (const int*)d_in[2];
  const int* cols1 = (const int*)d_in[3];
  const float* vals1 = (const float*)d_in[4];
  const int* rows2 = (const int*)d_in[5];
  const int* cols2 = (const int*)d_in[6];
  const float* vals2 = (const float*)d_in[7];
  const int* nu = (const int*)d_in[8];
  const int* ni = (const int*)d_in[9];
  int nE1 = in_sizes[2], nE2 = in_sizes[5];

  // workspace carve-out (256B aligned), total ~44.0 MB
  char* ws = (char*)d_ws;
  size_t o = 0;
  auto carve = [&](size_t bytes) {
    char* p = ws + o;
    o += (bytes + 255) & ~(size_t)255;
    return p;
  };
  int* map = (int*)carve(N_NODES * 4);
  float* z1acc = (float*)carve((size_t)SLOTS * DIM * 4);
  float* ttl = (float*)carve(SLOTS * 4);
  ushort* zallb = (ushort*)carve((size_t)N_NODES * DIM * 2);
  ushort* z1b = (ushort*)carve((size_t)SLOTS * DIM * 2);
  ushort* xb = (ushort*)carve((size_t)N_NODES * DIM * 2);
  int* head = (int*)carve(N_NODES * 4);
  u64* rec = (u64*)carve((size_t)nE2 * 8);
  float* out = (float*)d_out;

  hipMemsetAsync(map, 0xFF, N_NODES * 4, stream);  // -1
  hipMemsetAsync(head, 0, N_NODES * 4, stream);    // 0 = empty (+1 encoding)
  hipMemsetAsync(z1acc, 0, (size_t)SLOTS * DIM * 4, stream);
  hipMemsetAsync(ttl, 0, SLOTS * 4, stream);
  hipMemsetAsync(out, 0, sizeof(float), stream);

  build_map_kernel<<<16, 256, 0, stream>>>(nu, ni, map);
  ego2bf_kernel<<<(N_NODES * DIM / 4 + 255) / 256, 256, 0, stream>>>(ue, ie, xb);
  link2_kernel<<<(nE2 + 255) / 256, 256, 0, stream>>>(rows2, cols2, vals2, head, rec, nE2);
  gather_chain_norm_kernel<<<(N_NODES + 15) / 16, 256, 0, stream>>>(head, rec, xb, ue, ie, zallb);
  graph1_fused_kernel<<<(nE1 + 255) / 256, 256, 0, stream>>>(rows1, cols1, vals1, map, xb, z1acc, nE1);
  gather1_kernel<<<SLOTS / 4, 256, 0, stream>>>(ue, ie, nu, ni, map, z1acc, zallb, z1b, out);
  ttl_mfma_kernel<<<32 * TTL_STRIPS, 256, 0, stream>>>(z1b, zallb, ttl);
  final_kernel<<<16, 256, 0, stream>>>(ttl, out);
}

// Round 12
// 563.263 us; speedup vs baseline: 2.2958x; 1.0147x over previous
//
#include <hip/hip_runtime.h>
#include <hip/hip_bf16.h>
#include <hip/hip_fp16.h>
#include <math.h>

#define N_USERS 50000
#define N_ITEMS 50000
#define N_NODES 100000
#define DIM 64
#define BATCH 2048
#define SLOTS 4096

using frag_ab = __attribute__((ext_vector_type(8))) short;  // 8 bf16
using frag_cd = __attribute__((ext_vector_type(4))) float;  // 4 fp32
typedef unsigned long long u64;

// ---------------- helpers ----------------

__device__ __forceinline__ float wave_reduce_sum(float v) {
#pragma unroll
  for (int off = 32; off > 0; off >>= 1)
    v += __shfl_xor(v, off, 64);
  return v;
}

__device__ __forceinline__ const float* ego_row(const float* ue, const float* ie, int n) {
  return (n < N_USERS) ? (ue + (size_t)n * DIM) : (ie + (size_t)(n - N_USERS) * DIM);
}

__device__ __forceinline__ ushort f2bf(float x) {
  __hip_bfloat16 h = __float2bfloat16(x);
  return *(ushort*)&h;
}

__device__ __forceinline__ float bf2f(ushort u) {
  return __uint_as_float(((unsigned)u) << 16);
}

// ---------------- small setup kernels ----------------

__global__ void build_map_kernel(const int* __restrict__ nu, const int* __restrict__ ni,
                                 int* __restrict__ map) {
  int s = blockIdx.x * blockDim.x + threadIdx.x;
  if (s >= SLOTS) return;
  int n = (s < BATCH) ? nu[s] : (N_USERS + ni[s - BATCH]);
  map[n] = s;
}

// ego -> bf16 (concatenated node-major table xb[100000][64])
__global__ void ego2bf_kernel(const float* __restrict__ ue, const float* __restrict__ ie,
                              ushort* __restrict__ xb) {
  int t = blockIdx.x * blockDim.x + threadIdx.x;  // index of float4 group
  const int TOT = N_NODES * DIM / 4;
  if (t >= TOT) return;
  const int UH = N_USERS * DIM / 4;
  float4 f = (t < UH) ? ((const float4*)ue)[t] : ((const float4*)ie)[t - UH];
  ushort4 o;
  o.x = f2bf(f.x); o.y = f2bf(f.y); o.z = f2bf(f.z); o.w = f2bf(f.w);
  ((ushort4*)xb)[t] = o;
}

// ---------------- graph 2: per-row linked list, 8B records with val fused -----
// rec[e] = val_f16<<48 | col<<24 | (next+1). One atomicExch/edge; rec written
// coalesced by e. Walk touches ONE random line per step, no deg/vals lookups.
__global__ void link2_kernel(const int* __restrict__ rows, const int* __restrict__ cols,
                             const float* __restrict__ vals, int* __restrict__ head,
                             u64* __restrict__ rec, int nE) {
  int e = blockIdx.x * blockDim.x + threadIdx.x;
  if (e >= nE) return;
  int r = rows[e];
  int nx = atomicExch(&head[r], e + 1);  // head encoded +1, 0 = empty
  ushort hb = __half_as_ushort(__float2half(vals[e]));
  rec[e] = ((u64)hb << 48) | ((u64)(cols[e] & 0x1FFFF) << 24) | (u64)(unsigned)nx;
}

// ILP-8 + software-pipelined chain walk: each wave walks 8 node chains.
// Per iteration: from current record u[i], compute next ptr and ISSUE the next
// rec load immediately, then issue the xb gather for the current record, then
// fma. Critical path per step = one latency (next-rec); xb overlapped.
// ~16 VMEM outstanding per wave. All chain ptrs lane-uniform.
#define NCH 8
__global__ void gather_chain_norm_kernel(const int* __restrict__ head,
                                         const u64* __restrict__ rec,
                                         const ushort* __restrict__ xb,
                                         const float* __restrict__ ue,
                                         const float* __restrict__ ie,
                                         ushort* __restrict__ zallb) {
  int n0 = (blockIdx.x * 4 + (threadIdx.x >> 6)) * NCH;  // 8 nodes per wave
  if (n0 >= N_NODES) return;
  int lane = threadIdx.x & 63;
  float acc[NCH];
  int e[NCH];
  u64 u[NCH];
#pragma unroll
  for (int i = 0; i < NCH; i++) {
    acc[i] = 0.f;
    int n = n0 + i;
    e[i] = (n < N_NODES) ? head[n] : 0;
  }
#pragma unroll
  for (int i = 0; i < NCH; i++) u[i] = e[i] ? rec[e[i] - 1] : 0;  // prime pipeline

  while (e[0] | e[1] | e[2] | e[3] | e[4] | e[5] | e[6] | e[7]) {
    int en[NCH];
    u64 un[NCH];
    float x[NCH];
    // stage 1: advance pointers, issue NEXT-iteration rec loads early
#pragma unroll
    for (int i = 0; i < NCH; i++) {
      en[i] = e[i] ? (int)(u[i] & 0xFFFFFF) : 0;
      un[i] = en[i] ? rec[en[i] - 1] : 0;
    }
    // stage 2: issue current xb gathers (overlapped with the rec chases)
#pragma unroll
    for (int i = 0; i < NCH; i++)
      if (e[i]) {
        int c = (int)((u[i] >> 24) & 0x1FFFF);
        x[i] = bf2f(xb[(size_t)c * DIM + lane]);
      }
    // stage 3: accumulate, rotate pipeline state
#pragma unroll
    for (int i = 0; i < NCH; i++) {
      if (e[i]) {
        float v = __half2float(__ushort_as_half((ushort)(u[i] >> 48)));
        acc[i] = fmaf(v, x[i], acc[i]);
      }
      e[i] = en[i];
      u[i] = un[i];
    }
  }

#pragma unroll
  for (int i = 0; i < NCH; i++) {
    int n = n0 + i;
    if (n >= N_NODES) break;
    const float* eg = ego_row(ue, ie, n);
    float w = 0.5f * (eg[lane] + acc[i]);
    float ss = wave_reduce_sum(w * w);
    float z = w / fmaxf(sqrtf(ss), 1e-12f);
    zallb[(size_t)n * DIM + lane] = f2bf(z);
  }
}

// ---------------- graph 1: fused filter + accumulate ----------------
// Per-block LDS compaction, then the block's 4 waves gather xb rows and
// atomic-accumulate into the L2-resident 1MB z1acc.
__global__ __launch_bounds__(256) void graph1_fused_kernel(
    const int* __restrict__ rows, const int* __restrict__ cols,
    const float* __restrict__ vals, const int* __restrict__ map,
    const ushort* __restrict__ xb, float* __restrict__ z1acc, int nE) {
  __shared__ int lcount;
  __shared__ int hcol[256];
  __shared__ float hval[256];
  __shared__ int hslot[256];
  int tid = threadIdx.x;
  if (tid == 0) lcount = 0;
  __syncthreads();
  int e = blockIdx.x * 256 + tid;
  if (e < nE) {
    int r = rows[e];
    int s = map[r];
    if (s >= 0) {
      int pos = atomicAdd(&lcount, 1);  // LDS atomic - block-local
      hcol[pos] = cols[e];
      hval[pos] = vals[e];
      hslot[pos] = s;
    }
  }
  __syncthreads();
  int n = lcount;
  int wave = tid >> 6, lane = tid & 63;
  for (int k = wave; k < n; k += 4) {
    int c = hcol[k];
    float v = hval[k];
    int s = hslot[k];
    float x = bf2f(xb[(size_t)c * DIM + lane]);
    unsafeAtomicAdd(&z1acc[(size_t)s * DIM + lane], v * x);
  }
}

// z1 normalize (fp32) -> bf16; pos term out -= dot(z1, z2) with z2 from zallb.
__global__ void gather1_kernel(const float* __restrict__ ue, const float* __restrict__ ie,
                               const int* __restrict__ nu, const int* __restrict__ ni,
                               const int* __restrict__ map, const float* __restrict__ z1acc,
                               const ushort* __restrict__ zallb, ushort* __restrict__ z1b,
                               float* __restrict__ out) {
  int s = blockIdx.x * 4 + (threadIdx.x >> 6);
  if (s >= SLOTS) return;
  int lane = threadIdx.x & 63;
  int n = (s < BATCH) ? nu[s] : (N_USERS + ni[s - BATCH]);
  int fs = map[n];
  const float* e = ego_row(ue, ie, n);
  float v = 0.5f * (e[lane] + z1acc[(size_t)fs * DIM + lane]);
  float ss = wave_reduce_sum(v * v);
  float z = v / fmaxf(sqrtf(ss), 1e-12f);
  z1b[(size_t)s * DIM + lane] = f2bf(z);
  float dp = wave_reduce_sum(z * bf2f(zallb[(size_t)n * DIM + lane]));
  if (lane == 0) atomicAdd(out, -dp);
}

// ---------------- ttl (bf16 MFMA) ----------------
// Wave tile: M=32 z1 rows x 16 j per chunk, K=64 -> 4 MFMAs/chunk.
// Block = 4 waves = 128 rows, one strip of 25 chunks (400 j). Grid 32x125.
#define TTL_STRIPS 125
#define TTL_CHUNKS 25
__global__ __launch_bounds__(256) void ttl_mfma_kernel(const ushort* __restrict__ z1b,
                                                       const ushort* __restrict__ zallb,
                                                       float* __restrict__ ttl) {
  int rb = blockIdx.x / TTL_STRIPS;
  int strip = blockIdx.x % TTL_STRIPS;
  int wave = threadIdx.x >> 6;
  int lane = threadIdx.x & 63;
  int r0 = rb * 128 + wave * 32;
  int side = r0 >> 11;  // rows 0..2047 users, 2048..4095 items
  const ushort* zs = zallb + (size_t)side * N_USERS * DIM;

  int m = lane & 15, q = lane >> 4;
  const ushort* ar0 = z1b + (size_t)(r0 + m) * DIM + q * 8;
  frag_ab a00 = *(const frag_ab*)ar0;
  frag_ab a01 = *(const frag_ab*)(ar0 + 32);
  const ushort* ar1 = ar0 + 16 * DIM;
  frag_ab a10 = *(const frag_ab*)ar1;
  frag_ab a11 = *(const frag_ab*)(ar1 + 32);

  int j0 = strip * (TTL_CHUNKS * 16);
  const ushort* bp = zs + (size_t)(j0 + m) * DIM + q * 8;

  // depth-2 register pipeline on B
  frag_ab b0c = *(const frag_ab*)bp;
  frag_ab b1c = *(const frag_ab*)(bp + 32);
  const ushort* bp1 = bp + 16 * DIM;
  frag_ab b0n = *(const frag_ab*)bp1;
  frag_ab b1n = *(const frag_ab*)(bp1 + 32);

  float racc[8] = {0.f, 0.f, 0.f, 0.f, 0.f, 0.f, 0.f, 0.f};

  for (int c = 0; c < TTL_CHUNKS; c++) {
    frag_ab b0f = b0c, b1f = b1c;
    if (c + 2 < TTL_CHUNKS) {
      const ushort* bp2 = bp + 2 * 16 * DIM;
      b0f = *(const frag_ab*)bp2;
      b1f = *(const frag_ab*)(bp2 + 32);
    }
    frag_cd acc0 = {}, acc1 = {};
    acc0 = __builtin_amdgcn_mfma_f32_16x16x32_bf16(a00, b0c, acc0, 0, 0, 0);
    acc0 = __builtin_amdgcn_mfma_f32_16x16x32_bf16(a01, b1c, acc0, 0, 0, 0);
    acc1 = __builtin_amdgcn_mfma_f32_16x16x32_bf16(a10, b0c, acc1, 0, 0, 0);
    acc1 = __builtin_amdgcn_mfma_f32_16x16x32_bf16(a11, b1c, acc1, 0, 0, 0);
#pragma unroll
    for (int r = 0; r < 4; r++) {
      racc[r] += __expf(2.f * acc0[r]);
      racc[4 + r] += __expf(2.f * acc1[r]);
    }
    b0c = b0n; b1c = b1n;
    b0n = b0f; b1n = b1f;
    bp += 16 * DIM;
  }

  // C layout: col(=zall j) = lane&15, row(=z1 row) = q*4+reg. Reduce over j lanes.
#pragma unroll
  for (int h = 0; h < 2; h++) {
#pragma unroll
    for (int r = 0; r < 4; r++) {
      float v = racc[h * 4 + r];
      v += __shfl_xor(v, 1, 64);
      v += __shfl_xor(v, 2, 64);
      v += __shfl_xor(v, 4, 64);
      v += __shfl_xor(v, 8, 64);
      if (m == 0) atomicAdd(&ttl[r0 + h * 16 + q * 4 + r], v);
    }
  }
}

// out += 0.5 * sum_i log(ttl[i])
__global__ void final_kernel(const float* __restrict__ ttl, float* __restrict__ out) {
  int t = blockIdx.x * blockDim.x + threadIdx.x;
  float v = (t < SLOTS) ? 0.5f * logf(ttl[t]) : 0.f;
  v = wave_reduce_sum(v);
  if ((threadIdx.x & 63) == 0) atomicAdd(out, v);
}

// ---------------- launch ----------------

extern "C" void kernel_launch(void* const* d_in, const int* in_sizes, int n_in,
                              void* d_out, int out_size, void* d_ws, size_t ws_size,
                              hipStream_t stream) {
  const float* ue = (const float*)d_in[0];
  const float* ie = (const float*)d_in[1];
  const int* rows1 = (const int*)d_in[2];
  const int* cols1 = (const int*)d_in[3];
  const float* vals1 = (const float*)d_in[4];
  const int* rows2 = (const int*)d_in[5];
  const int* cols2 = (const int*)d_in[6];
  const float* vals2 = (const float*)d_in[7];
  const int* nu = (const int*)d_in[8];
  const int* ni = (const int*)d_in[9];
  int nE1 = in_sizes[2], nE2 = in_sizes[5];

  // workspace carve-out (256B aligned), total ~44.0 MB
  char* ws = (char*)d_ws;
  size_t o = 0;
  auto carve = [&](size_t bytes) {
    char* p = ws + o;
    o += (bytes + 255) & ~(size_t)255;
    return p;
  };
  int* map = (int*)carve(N_NODES * 4);
  float* z1acc = (float*)carve((size_t)SLOTS * DIM * 4);
  float* ttl = (float*)carve(SLOTS * 4);
  ushort* zallb = (ushort*)carve((size_t)N_NODES * DIM * 2);
  ushort* z1b = (ushort*)carve((size_t)SLOTS * DIM * 2);
  ushort* xb = (ushort*)carve((size_t)N_NODES * DIM * 2);
  int* head = (int*)carve(N_NODES * 4);
  u64* rec = (u64*)carve((size_t)nE2 * 8);
  float* out = (float*)d_out;

  hipMemsetAsync(map, 0xFF, N_NODES * 4, stream);  // -1
  hipMemsetAsync(head, 0, N_NODES * 4, stream);    // 0 = empty (+1 encoding)
  hipMemsetAsync(z1acc, 0, (size_t)SLOTS * DIM * 4, stream);
  hipMemsetAsync(ttl, 0, SLOTS * 4, stream);
  hipMemsetAsync(out, 0, sizeof(float), stream);

  build_map_kernel<<<16, 256, 0, stream>>>(nu, ni, map);
  ego2bf_kernel<<<(N_NODES * DIM / 4 + 255) / 256, 256, 0, stream>>>(ue, ie, xb);
  link2_kernel<<<(nE2 + 255) / 256, 256, 0, stream>>>(rows2, cols2, vals2, head, rec, nE2);
  gather_chain_norm_kernel<<<(N_NODES + 4 * NCH - 1) / (4 * NCH), 256, 0, stream>>>(
      head, rec, xb, ue, ie, zallb);
  graph1_fused_kernel<<<(nE1 + 255) / 256, 256, 0, stream>>>(rows1, cols1, vals1, map, xb, z1acc, nE1);
  gather1_kernel<<<SLOTS / 4, 256, 0, stream>>>(ue, ie, nu, ni, map, z1acc, zallb, z1b, out);
  ttl_mfma_kernel<<<32 * TTL_STRIPS, 256, 0, stream>>>(z1b, zallb, ttl);
  final_kernel<<<16, 256, 0, stream>>>(ttl, out);
}